// Round 9
// baseline (147.175 us; speedup 1.0000x reference)
//
#include <hip/hip_runtime.h>
#include <math.h>

#define N_V 12288
#define D_F 32
#define N_E 196608
#define KNN 6
#define EPSF 1e-12f

#define SEGS 16
#define JSEG (N_V / SEGS)          // 768 candidate columns per segment
#define SUBTILES (JSEG / 16)       // 48 j-subtiles per segment
#define BLOCK_T 256                // 4 waves
#define ROWS_PER_BLOCK 256         // 4 waves x 64 query rows (4 B-frags/wave)
#define ROW_BLOCKS (N_V / ROWS_PER_BLOCK)  // 48 topk tiles x 16 segs = 768 topk blocks
#define NKEEP 5                    // top-5 non-self keys kept per (row, seg)
#define NEGF -3.0e38f

typedef __bf16 bf16x8 __attribute__((ext_vector_type(8)));
typedef float f32x4 __attribute__((ext_vector_type(4)));

static_assert(N_V % ROWS_PER_BLOCK == 0, "");
static_assert(N_E == 768 * 256, "");

__device__ __forceinline__ unsigned short f2bf(float f) {
    unsigned u = __builtin_bit_cast(unsigned, f);
    unsigned r = u + 0x7fffu + ((u >> 16) & 1u);   // RNE
    return (unsigned short)(r >> 16);
}

__device__ __forceinline__ float bfu2f(unsigned hw_lo16) {   // low 16 bits -> float
    return __builtin_bit_cast(float, hw_lo16 << 16);
}
__device__ __forceinline__ float bfhi2f(unsigned u) {        // high 16 bits -> float
    return __builtin_bit_cast(float, u & 0xffff0000u);
}

// descending sorted 5-list insert: 1 max + 4 med3 (med3 full-rate; R4 proved
// the 9-op min/max variant strictly worse)
__device__ __forceinline__ void ins5(float s[NKEEP], float nv) {
    float y0 = fmaxf(s[0], nv);
    float y1 = __builtin_amdgcn_fmed3f(s[0], s[1], nv);
    float y2 = __builtin_amdgcn_fmed3f(s[1], s[2], nv);
    float y3 = __builtin_amdgcn_fmed3f(s[2], s[3], nv);
    float y4 = __builtin_amdgcn_fmed3f(s[3], s[4], nv);
    s[0] = y0; s[1] = y1; s[2] = y2; s[3] = y3; s[4] = y4;
}

// ---------- kernel 0: bf16 convert + msq(-0.5*sq), 8 threads/row ----------
__global__ __launch_bounds__(256) void prep_kernel(const float* __restrict__ x,
                                                   unsigned short* __restrict__ xb,
                                                   float* __restrict__ msq) {
    const int gid = blockIdx.x * 256 + threadIdx.x;   // 0..98303
    const int row = gid >> 3;
    const int h = gid & 7;
    float4 p = ((const float4*)(x + (size_t)row * D_F))[h];
    float s = p.x * p.x + p.y * p.y + p.z * p.z + p.w * p.w;
    s += __shfl_xor(s, 1, 64);
    s += __shfl_xor(s, 2, 64);
    s += __shfl_xor(s, 4, 64);
    const unsigned lo = (unsigned)f2bf(p.x) | ((unsigned)f2bf(p.y) << 16);
    const unsigned hi = (unsigned)f2bf(p.z) | ((unsigned)f2bf(p.w) << 16);
    ((uint2*)xb)[gid] = make_uint2(lo, hi);
    if (h == 0) msq[row] = -0.5f * s;
}

// ---------- kernel 1: co-resident topk (even 8-chunks) + edge-ey (odd 8-chunks) ----------
// Role by (blockIdx.x>>3)&1 so round-robin XCD dispatch gives every XCD both
// roles (parity split would segregate roles by XCD). topk: R8's proven 4-wide
// loop with GLOBAL A/msq + 1-deep prefetch (R2-proven 46us, zero LDS) so edge
// blocks co-occupy CUs (6 blocks = 24 waves/CU). Edge-ey blocks fill topk's
// ~65% idle issue/VMEM slots with the gather-latency-bound norm computation.
// topk is a measured local floor at 42.6us (R3/R8 identical across 5 schedule
// variants); this round attacks the serial residual instead.
__global__ __launch_bounds__(BLOCK_T, 4) void mega_kernel(
    const unsigned short* __restrict__ xb, const float* __restrict__ msq,
    float* __restrict__ cand, const int* __restrict__ ei,
    float* __restrict__ out) {
    const int role = (blockIdx.x >> 3) & 1;
    const int w = (int)((blockIdx.x >> 4) << 3) | (int)(blockIdx.x & 7);  // 0..767
    const int t = threadIdx.x;

    if (role == 1) {
        // ---- edge-ey: 256 edges/block, needs only xb ----
        const int e = w * 256 + t;
        const int u = ei[e];
        const int ww = ei[N_E + e];
        const uint4* xu = (const uint4*)(xb + (size_t)u * D_F);
        const uint4* xw = (const uint4*)(xb + (size_t)ww * D_F);
        float acc = 0.f;
#pragma unroll
        for (int d = 0; d < 4; ++d) {
            const uint4 p = xu[d];
            const uint4 q = xw[d];
#pragma unroll
            for (int c = 0; c < 4; ++c) {
                const unsigned pu = (&p.x)[c];
                const unsigned qu = (&q.x)[c];
                const float d0 = bfu2f(pu) - bfu2f(qu);
                const float d1 = bfhi2f(pu) - bfhi2f(qu);
                acc = fmaf(d0, d0, acc);
                acc = fmaf(d1, d1, acc);
            }
        }
        const float enorm = sqrtf(fmaxf(acc, EPSF));
        out[2 * (N_V + e) + 1] = 1.0f - expf(-enorm);
        return;
    }

    // ---- topk role ----
    const int wave = t >> 6;
    const int lane = t & 63;
    const int quad = lane >> 4;
    const int l16 = lane & 15;

    const int rb = w % ROW_BLOCKS;
    const int seg = w / ROW_BLOCKS;
    const int rowbase = rb * ROWS_PER_BLOCK + wave * 64;
    const int j0 = seg * JSEG;

    // B fragments: 4 x 16 query rows, register-resident
    bf16x8 bfrag[4];
#pragma unroll
    for (int rt = 0; rt < 4; ++rt)
        bfrag[rt] = *reinterpret_cast<const bf16x8*>(
            xb + (size_t)(rowbase + rt * 16 + l16) * D_F + quad * 8);

    float tk[4][NKEEP];
#pragma unroll
    for (int rt = 0; rt < 4; ++rt)
#pragma unroll
        for (int k = 0; k < NKEEP; ++k) tk[rt][k] = NEGF;

    // lane's self position inside a matching subtile: quad*4+reg == l16
    const int selfreg = (quad == (l16 >> 2)) ? (l16 & 3) : 8;

    const unsigned short* aptr = xb + (size_t)(j0 + l16) * D_F + quad * 8;
    const float* mptr = msq + j0 + quad * 4;

    // 1-deep prefetch (R2-proven); clamped last-iteration reload, no over-read
    bf16x8 a_c = *reinterpret_cast<const bf16x8*>(aptr);
    f32x4 m_c = *reinterpret_cast<const f32x4*>(mptr);

    for (int it = 0; it < SUBTILES; ++it) {
        const int itn = (it + 1 < SUBTILES) ? it + 1 : SUBTILES - 1;
        const bf16x8 a_n = *reinterpret_cast<const bf16x8*>(aptr + itn * (16 * D_F));
        const f32x4 m_n = *reinterpret_cast<const f32x4*>(mptr + itn * 16);

        f32x4 c0 = __builtin_amdgcn_mfma_f32_16x16x32_bf16(a_c, bfrag[0], m_c, 0, 0, 0);
        f32x4 c1 = __builtin_amdgcn_mfma_f32_16x16x32_bf16(a_c, bfrag[1], m_c, 0, 0, 0);
        f32x4 c2 = __builtin_amdgcn_mfma_f32_16x16x32_bf16(a_c, bfrag[2], m_c, 0, 0, 0);
        f32x4 c3 = __builtin_amdgcn_mfma_f32_16x16x32_bf16(a_c, bfrag[3], m_c, 0, 0, 0);

        const int jt = j0 + (it << 4);
        if (jt == rowbase) {          // wave-uniform: rt=0 self diag in this subtile
            c0[0] = (selfreg == 0) ? NEGF : c0[0];
            c0[1] = (selfreg == 1) ? NEGF : c0[1];
            c0[2] = (selfreg == 2) ? NEGF : c0[2];
            c0[3] = (selfreg == 3) ? NEGF : c0[3];
        }
        if (jt == rowbase + 16) {     // rt=1
            c1[0] = (selfreg == 0) ? NEGF : c1[0];
            c1[1] = (selfreg == 1) ? NEGF : c1[1];
            c1[2] = (selfreg == 2) ? NEGF : c1[2];
            c1[3] = (selfreg == 3) ? NEGF : c1[3];
        }
        if (jt == rowbase + 32) {     // rt=2
            c2[0] = (selfreg == 0) ? NEGF : c2[0];
            c2[1] = (selfreg == 1) ? NEGF : c2[1];
            c2[2] = (selfreg == 2) ? NEGF : c2[2];
            c2[3] = (selfreg == 3) ? NEGF : c2[3];
        }
        if (jt == rowbase + 48) {     // rt=3
            c3[0] = (selfreg == 0) ? NEGF : c3[0];
            c3[1] = (selfreg == 1) ? NEGF : c3[1];
            c3[2] = (selfreg == 2) ? NEGF : c3[2];
            c3[3] = (selfreg == 3) ? NEGF : c3[3];
        }

        ins5(tk[0], c0[0]); ins5(tk[0], c0[1]); ins5(tk[0], c0[2]); ins5(tk[0], c0[3]);
        ins5(tk[1], c1[0]); ins5(tk[1], c1[1]); ins5(tk[1], c1[2]); ins5(tk[1], c1[3]);
        ins5(tk[2], c2[0]); ins5(tk[2], c2[1]); ins5(tk[2], c2[2]); ins5(tk[2], c2[3]);
        ins5(tk[3], c3[0]); ins5(tk[3], c3[1]); ins5(tk[3], c3[2]); ins5(tk[3], c3[3]);

        a_c = a_n; m_c = m_n;
    }

    // ---- cross-quad merge via shuffles (row's lists live in 4 quads, same l16) ----
#pragma unroll
    for (int rt = 0; rt < 4; ++rt) {
#pragma unroll
        for (int rnd = 0; rnd < 2; ++rnd) {
            const int mask = 16 << rnd;
            float b[NKEEP];
#pragma unroll
            for (int k = 0; k < NKEEP; ++k) b[k] = __shfl_xor(tk[rt][k], mask, 64);
#pragma unroll
            for (int k = 0; k < NKEEP; ++k) ins5(tk[rt], b[k]);
        }
    }

    if (quad == 0) {
#pragma unroll
        for (int rt = 0; rt < 4; ++rt) {
            const int g = rowbase + rt * 16 + l16;
            float* dst = cand + ((size_t)g * SEGS + seg) * NKEEP;
#pragma unroll
            for (int k = 0; k < NKEEP; ++k) dst[k] = tk[rt][k];
        }
    }
}

// ---------- kernel 2: merge per-segment keys -> v, 4 threads/row ----------
__global__ __launch_bounds__(256) void merge_v(const float* __restrict__ cand,
                                               const float* __restrict__ msq,
                                               float* __restrict__ v,
                                               float* __restrict__ out) {
    const int gid = blockIdx.x * 256 + threadIdx.x;   // 0..49151
    const int row = gid >> 2;
    const int h = gid & 3;
    const float4* c = (const float4*)(cand + (size_t)row * (SEGS * NKEEP));  // 20 x float4
    float mk[NKEEP];
#pragma unroll
    for (int k = 0; k < NKEEP; ++k) mk[k] = NEGF;
#pragma unroll
    for (int s = 0; s < 5; ++s) {
        float4 q = c[h + 4 * s];
        ins5(mk, q.x); ins5(mk, q.y); ins5(mk, q.z); ins5(mk, q.w);
    }
    // merge across the 4 lanes of this row (consecutive lanes, same wave)
#pragma unroll
    for (int rnd = 0; rnd < 2; ++rnd) {
        const int mask = 1 << rnd;
        float b[NKEEP];
#pragma unroll
        for (int k = 0; k < NKEEP; ++k) b[k] = __shfl_xor(mk[k], mask, 64);
#pragma unroll
        for (int k = 0; k < NKEEP; ++k) ins5(mk, b[k]);
    }
    if (h == 0) {
        const float msqi = msq[row];
        float ssum = 0.f;
#pragma unroll
        for (int m = 0; m < NKEEP; ++m) {
            const float d2 = -2.0f * (mk[m] + msqi);   // sq_i - 2*key
            ssum += expf(-sqrtf(fmaxf(d2, EPSF)));
        }
        const float vi = 1.0f - ssum / (float)KNN;
        v[row] = vi;
        out[2 * row] = vi;
        out[2 * row + 1] = 0.0f;
    }
}

// ---------- kernel 3: edge ev = max(v[u], v[w]) (v table is L1/L2-resident) ----------
__global__ __launch_bounds__(256) void edge_ev(const int* __restrict__ ei,
                                               const float* __restrict__ v,
                                               float* __restrict__ out) {
    const int e = blockIdx.x * 256 + threadIdx.x;
    const int u = ei[e];
    const int w = ei[N_E + e];
    out[2 * (N_V + e)] = fmaxf(v[u], v[w]);
}

extern "C" void kernel_launch(void* const* d_in, const int* in_sizes, int n_in,
                              void* d_out, int out_size, void* d_ws, size_t ws_size,
                              hipStream_t stream) {
    const float* x = (const float*)d_in[0];
    const int* ei = (const int*)d_in[1];
    float* out = (float*)d_out;
    char* ws = (char*)d_ws;

    unsigned short* xb = (unsigned short*)ws;                  // 786432 B
    float* msq = (float*)(ws + 786432);                        // 49152 B
    float* v   = (float*)(ws + 786432 + 49152);                // 49152 B
    float* cand = (float*)(ws + 786432 + 2 * 49152);           // 12288*16*5*4 = 3932160 B

    prep_kernel<<<(N_V * 8) / 256, 256, 0, stream>>>(x, xb, msq);

    mega_kernel<<<2 * 768, BLOCK_T, 0, stream>>>(xb, msq, cand, ei, out);

    merge_v<<<(N_V * 4) / 256, 256, 0, stream>>>(cand, msq, v, out);

    edge_ev<<<N_E / 256, 256, 0, stream>>>(ei, v, out);
}

// Round 10
// 99.923 us; speedup vs baseline: 1.4729x; 1.4729x over previous
//
#include <hip/hip_runtime.h>
#include <math.h>

#define N_V 12288
#define D_F 32
#define N_E 196608
#define KNN 6
#define EPSF 1e-12f

#define SEGS 16
#define JSEG (N_V / SEGS)          // 768 candidate columns per segment
#define SUBTILES (JSEG / 16)       // 48 j-subtiles per segment
#define BLOCK_T 256                // 4 waves
#define ROWS_PER_BLOCK 256         // 4 waves x 64 query rows (4 B-frags/wave)
#define ROW_BLOCKS (N_V / ROWS_PER_BLOCK)  // 48 -> grid 48 x 16 = 768 blocks (3/CU)
#define NKEEP 5                    // top-5 non-self keys kept per (row, seg)
#define NEGF -3.0e38f

#define A_BYTES (JSEG * 64)        // 49152: A tiles, fragment-linear
#define M_OFF A_BYTES              // msq region at 49152
#define LDS_BYTES (A_BYTES + JSEG * 4)  // 52224 (R3/R8-proven config)

typedef __bf16 bf16x8 __attribute__((ext_vector_type(8)));
typedef float f32x4 __attribute__((ext_vector_type(4)));

static_assert(N_V % ROWS_PER_BLOCK == 0, "");
static_assert(SUBTILES % 4 == 0, "");

__device__ __forceinline__ unsigned short f2bf(float f) {
    unsigned u = __builtin_bit_cast(unsigned, f);
    unsigned r = u + 0x7fffu + ((u >> 16) & 1u);   // RNE
    return (unsigned short)(r >> 16);
}

__device__ __forceinline__ float bfu2f(unsigned hw_lo16) {   // low 16 bits -> float
    return __builtin_bit_cast(float, hw_lo16 << 16);
}
__device__ __forceinline__ float bfhi2f(unsigned u) {        // high 16 bits -> float
    return __builtin_bit_cast(float, u & 0xffff0000u);
}

// descending sorted 5-list insert: 1 max + 4 med3 (med3 full-rate; R4 proved
// the 9-op min/max variant strictly worse)
__device__ __forceinline__ void ins5(float s[NKEEP], float nv) {
    float y0 = fmaxf(s[0], nv);
    float y1 = __builtin_amdgcn_fmed3f(s[0], s[1], nv);
    float y2 = __builtin_amdgcn_fmed3f(s[1], s[2], nv);
    float y3 = __builtin_amdgcn_fmed3f(s[2], s[3], nv);
    float y4 = __builtin_amdgcn_fmed3f(s[3], s[4], nv);
    s[0] = y0; s[1] = y1; s[2] = y2; s[3] = y3; s[4] = y4;
}

// ---------- kernel 0: bf16 convert + msq(-0.5*sq), 8 threads/row ----------
__global__ __launch_bounds__(256) void prep_kernel(const float* __restrict__ x,
                                                   unsigned short* __restrict__ xb,
                                                   float* __restrict__ msq) {
    const int gid = blockIdx.x * 256 + threadIdx.x;   // 0..98303
    const int row = gid >> 3;
    const int h = gid & 7;
    float4 p = ((const float4*)(x + (size_t)row * D_F))[h];
    float s = p.x * p.x + p.y * p.y + p.z * p.z + p.w * p.w;
    s += __shfl_xor(s, 1, 64);
    s += __shfl_xor(s, 2, 64);
    s += __shfl_xor(s, 4, 64);
    const unsigned lo = (unsigned)f2bf(p.x) | ((unsigned)f2bf(p.y) << 16);
    const unsigned hi = (unsigned)f2bf(p.z) | ((unsigned)f2bf(p.w) << 16);
    ((uint2*)xb)[gid] = make_uint2(lo, hi);
    if (h == 0) msq[row] = -0.5f * s;
}

// ---------- kernel 1: MFMA gram + per-row top-5 (non-self) keys ----------
// R8 verbatim EXCEPT one variable: the 16 ins5 calls per subtile are emitted
// round-robin across the 4 independent rt-chains (value-index outer, rt inner)
// so consecutive inserts into the SAME list are separated by ~15 issued ops —
// in-order issue never stalls on the ins5->ins5 dependency (~10-12 cyc).
// Pure source reorder: zero extra ops, no pins, no pressure change.
__global__ __launch_bounds__(BLOCK_T, 3) void topk_mfma(
    const unsigned short* __restrict__ xb, const float* __restrict__ msq,
    float* __restrict__ cand) {
    __shared__ alignas(16) char lds[LDS_BYTES];
    const int t = threadIdx.x;
    const int wave = t >> 6;
    const int lane = t & 63;
    const int quad = lane >> 4;
    const int l16 = lane & 15;

    const int rowbase = blockIdx.x * ROWS_PER_BLOCK + wave * 64;
    const int seg = blockIdx.y;
    const int j0 = seg * JSEG;

    // ---- stage segment A-tiles into LDS (each of 4 waves: 12 subtiles) ----
#pragma unroll
    for (int k = 0; k < SUBTILES / 4; ++k) {
        const int it = wave + 4 * k;
        const uint4 val = *((const uint4*)(xb + (size_t)(j0 + it * 16 + l16) * D_F) + quad);
        *((uint4*)(lds + it * 1024) + lane) = val;
    }
    if (wave == 0) {
#pragma unroll
        for (int k = 0; k < 3; ++k) {
            const uint4 val = *((const uint4*)(msq + j0) + k * 64 + lane);
            *((uint4*)(lds + M_OFF + k * 1024) + lane) = val;
        }
    }

    // B fragments: 4 x 16 query rows, register-resident
    bf16x8 bfrag[4];
#pragma unroll
    for (int rt = 0; rt < 4; ++rt)
        bfrag[rt] = *reinterpret_cast<const bf16x8*>(
            xb + (size_t)(rowbase + rt * 16 + l16) * D_F + quad * 8);

    __syncthreads();

    float tk[4][NKEEP];
#pragma unroll
    for (int rt = 0; rt < 4; ++rt)
#pragma unroll
        for (int k = 0; k < NKEEP; ++k) tk[rt][k] = NEGF;

    // lane's self position inside a matching subtile: quad*4+reg == l16
    const int selfreg = (quad == (l16 >> 2)) ? (l16 & 3) : 8;

    const char* aBase = lds + lane * 16;
    const char* mBase = lds + M_OFF + quad * 16;

#pragma unroll
    for (int it = 0; it < SUBTILES; ++it) {
        const bf16x8 a = *reinterpret_cast<const bf16x8*>(aBase + it * 1024);
        const f32x4 m = *reinterpret_cast<const f32x4*>(mBase + it * 64);

        f32x4 c[4];
        c[0] = __builtin_amdgcn_mfma_f32_16x16x32_bf16(a, bfrag[0], m, 0, 0, 0);
        c[1] = __builtin_amdgcn_mfma_f32_16x16x32_bf16(a, bfrag[1], m, 0, 0, 0);
        c[2] = __builtin_amdgcn_mfma_f32_16x16x32_bf16(a, bfrag[2], m, 0, 0, 0);
        c[3] = __builtin_amdgcn_mfma_f32_16x16x32_bf16(a, bfrag[3], m, 0, 0, 0);

        const int jt = j0 + (it << 4);
#pragma unroll
        for (int rt = 0; rt < 4; ++rt) {
            if (jt == rowbase + rt * 16) {   // wave-uniform self-diag poison
                c[rt][0] = (selfreg == 0) ? NEGF : c[rt][0];
                c[rt][1] = (selfreg == 1) ? NEGF : c[rt][1];
                c[rt][2] = (selfreg == 2) ? NEGF : c[rt][2];
                c[rt][3] = (selfreg == 3) ? NEGF : c[rt][3];
            }
        }

        // round-robin interleave: value-index outer, rt-chain inner
#pragma unroll
        for (int vv = 0; vv < 4; ++vv) {
            ins5(tk[0], c[0][vv]);
            ins5(tk[1], c[1][vv]);
            ins5(tk[2], c[2][vv]);
            ins5(tk[3], c[3][vv]);
        }
    }

    // ---- cross-quad merge via shuffles (rt-interleaved for the same reason) ----
#pragma unroll
    for (int rnd = 0; rnd < 2; ++rnd) {
        const int mask = 16 << rnd;
        float b[4][NKEEP];
#pragma unroll
        for (int rt = 0; rt < 4; ++rt)
#pragma unroll
            for (int k = 0; k < NKEEP; ++k) b[rt][k] = __shfl_xor(tk[rt][k], mask, 64);
#pragma unroll
        for (int k = 0; k < NKEEP; ++k) {
            ins5(tk[0], b[0][k]);
            ins5(tk[1], b[1][k]);
            ins5(tk[2], b[2][k]);
            ins5(tk[3], b[3][k]);
        }
    }

    if (quad == 0) {
#pragma unroll
        for (int rt = 0; rt < 4; ++rt) {
            const int g = rowbase + rt * 16 + l16;
            float* dst = cand + ((size_t)g * SEGS + seg) * NKEEP;
#pragma unroll
            for (int k = 0; k < NKEEP; ++k) dst[k] = tk[rt][k];
        }
    }
}

// ---------- kernel 2: merge per-segment keys -> v, 4 threads/row ----------
__global__ __launch_bounds__(256) void merge_v(const float* __restrict__ cand,
                                               const float* __restrict__ msq,
                                               float* __restrict__ v,
                                               float* __restrict__ out) {
    const int gid = blockIdx.x * 256 + threadIdx.x;   // 0..49151
    const int row = gid >> 2;
    const int h = gid & 3;
    const float4* c = (const float4*)(cand + (size_t)row * (SEGS * NKEEP));  // 20 x float4
    float mk[NKEEP];
#pragma unroll
    for (int k = 0; k < NKEEP; ++k) mk[k] = NEGF;
#pragma unroll
    for (int s = 0; s < 5; ++s) {
        float4 q = c[h + 4 * s];
        ins5(mk, q.x); ins5(mk, q.y); ins5(mk, q.z); ins5(mk, q.w);
    }
    // merge across the 4 lanes of this row (consecutive lanes, same wave)
#pragma unroll
    for (int rnd = 0; rnd < 2; ++rnd) {
        const int mask = 1 << rnd;
        float b[NKEEP];
#pragma unroll
        for (int k = 0; k < NKEEP; ++k) b[k] = __shfl_xor(mk[k], mask, 64);
#pragma unroll
        for (int k = 0; k < NKEEP; ++k) ins5(mk, b[k]);
    }
    if (h == 0) {
        const float msqi = msq[row];
        float ssum = 0.f;
#pragma unroll
        for (int m = 0; m < NKEEP; ++m) {
            const float d2 = -2.0f * (mk[m] + msqi);   // sq_i - 2*key
            ssum += expf(-sqrtf(fmaxf(d2, EPSF)));
        }
        const float vi = 1.0f - ssum / (float)KNN;
        v[row] = vi;
        out[2 * row] = vi;
        out[2 * row + 1] = 0.0f;
    }
}

// ---------- kernel 3: edge filtration (bf16 gather: 1 line per row) ----------
__global__ __launch_bounds__(256) void edge_kernel(const unsigned short* __restrict__ xb,
                                                   const int* __restrict__ ei,
                                                   const float* __restrict__ v,
                                                   float* __restrict__ out) {
    int e = blockIdx.x * 256 + threadIdx.x;
    if (e >= N_E) return;
    const int u = ei[e];
    const int w = ei[N_E + e];
    const uint4* xu = (const uint4*)(xb + (size_t)u * D_F);
    const uint4* xw = (const uint4*)(xb + (size_t)w * D_F);
    float acc = 0.f;
#pragma unroll
    for (int d = 0; d < 4; ++d) {
        const uint4 p = xu[d];
        const uint4 q = xw[d];
#pragma unroll
        for (int c = 0; c < 4; ++c) {
            const unsigned pu = (&p.x)[c];
            const unsigned qu = (&q.x)[c];
            const float d0 = bfu2f(pu) - bfu2f(qu);
            const float d1 = bfhi2f(pu) - bfhi2f(qu);
            acc = fmaf(d0, d0, acc);
            acc = fmaf(d1, d1, acc);
        }
    }
    const float enorm = sqrtf(fmaxf(acc, EPSF));
    const float ey = 1.0f - expf(-enorm);
    const float ev = fmaxf(v[u], v[w]);
    out[2 * (N_V + e) + 0] = ev;
    out[2 * (N_V + e) + 1] = ey;
}

extern "C" void kernel_launch(void* const* d_in, const int* in_sizes, int n_in,
                              void* d_out, int out_size, void* d_ws, size_t ws_size,
                              hipStream_t stream) {
    const float* x = (const float*)d_in[0];
    const int* ei = (const int*)d_in[1];
    float* out = (float*)d_out;
    char* ws = (char*)d_ws;

    unsigned short* xb = (unsigned short*)ws;                  // 786432 B
    float* msq = (float*)(ws + 786432);                        // 49152 B
    float* v   = (float*)(ws + 786432 + 49152);                // 49152 B
    float* cand = (float*)(ws + 786432 + 2 * 49152);           // 12288*16*5*4 = 3932160 B

    prep_kernel<<<(N_V * 8) / 256, 256, 0, stream>>>(x, xb, msq);

    dim3 g1(ROW_BLOCKS, SEGS);
    topk_mfma<<<g1, BLOCK_T, 0, stream>>>(xb, msq, cand);

    merge_v<<<(N_V * 4) / 256, 256, 0, stream>>>(cand, msq, v, out);

    edge_kernel<<<N_E / 256, 256, 0, stream>>>(xb, ei, v, out);
}